// Round 1
// baseline (115.753 us; speedup 1.0000x reference)
//
#include <hip/hip_runtime.h>

// TopDownHTMM fused forward.
// 512 blocks = (tree, g) pairs; heap-structured binary trees, contiguous per tree.
// LDS buffer slot per node holds prior -> ratio(beta/prior) -> eps over the 3 passes.

#define NTREES 64
#define DEPTH  10
#define C      8
#define M      32
#define G      8
#define NPT    2047          // 2^(DEPTH+1)-1 nodes per tree
#define PAD    9             // floats per node slot (9 coprime with 32 banks)
#define BLOCK  256

__global__ __launch_bounds__(BLOCK, 2)
void htmm_kernel(const float* __restrict__ A,   // (C,C,G)
                 const float* __restrict__ B,   // (C,M,G)
                 const float* __restrict__ Pi,  // (C,G)
                 const int*   __restrict__ x,   // (DIM,)
                 float* __restrict__ out)       // (NTREES,G)
{
    __shared__ float buf[NPT * PAD];            // 73,692 B
    __shared__ float sA[C][C],  lgA[C][C];      // sA[i][j] = softmax_i A[i,j,g]
    __shared__ float sB[C][M],  lgB[C][M];      // softmax over m
    __shared__ float spi[C],    lgpi[C];
    __shared__ float red[BLOCK];

    const int b   = blockIdx.x;
    const int t   = b >> 3;                     // tree
    const int g   = b & 7;                      // group
    const int tid = threadIdx.x;
    const int nodeBase = t * NPT;

    // ---------- per-g softmaxes of parameters ----------
    if (tid < C) {                              // A column j=tid, softmax over i
        const int j = tid;
        float v[C]; float mx = -1e30f;
        for (int i = 0; i < C; ++i) { v[i] = A[(i*C + j)*G + g]; mx = fmaxf(mx, v[i]); }
        float s = 0.f;
        for (int i = 0; i < C; ++i) { v[i] = expf(v[i] - mx); s += v[i]; }
        const float inv = 1.f / s;
        for (int i = 0; i < C; ++i) { const float sm = v[i]*inv; sA[i][j] = sm; lgA[i][j] = logf(sm); }
    } else if (tid >= 64 && tid < 64 + C) {     // B row c, softmax over m
        const int c = tid - 64;
        float v[M]; float mx = -1e30f;
        for (int m = 0; m < M; ++m) { v[m] = B[(c*M + m)*G + g]; mx = fmaxf(mx, v[m]); }
        float s = 0.f;
        for (int m = 0; m < M; ++m) { v[m] = expf(v[m] - mx); s += v[m]; }
        const float inv = 1.f / s;
        for (int m = 0; m < M; ++m) { const float sm = v[m]*inv; sB[c][m] = sm; lgB[c][m] = logf(sm); }
    } else if (tid == 128) {                    // Pi, softmax over c
        float v[C]; float mx = -1e30f;
        for (int c = 0; c < C; ++c) { v[c] = Pi[c*G + g]; mx = fmaxf(mx, v[c]); }
        float s = 0.f;
        for (int c = 0; c < C; ++c) { v[c] = expf(v[c] - mx); s += v[c]; }
        const float inv = 1.f / s;
        for (int c = 0; c < C; ++c) { const float sm = v[c]*inv; spi[c] = sm; lgpi[c] = logf(sm); }
    }
    __syncthreads();

    // ---------- pass 1: prior (top-down) ----------
    if (tid == 0) {
        for (int i = 0; i < C; ++i) buf[i] = spi[i];
    }
    __syncthreads();
    for (int d = 1; d <= DEPTH; ++d) {
        const int start = (1 << d) - 1, cnt = 1 << d;
        for (int v = start + tid; v < start + cnt; v += BLOCK) {
            const int pa = (v - 1) >> 1;
            float p[C];
            #pragma unroll
            for (int j = 0; j < C; ++j) p[j] = buf[pa*PAD + j];
            #pragma unroll
            for (int i = 0; i < C; ++i) {
                float acc = 0.f;
                #pragma unroll
                for (int j = 0; j < C; ++j) acc += sA[i][j] * p[j];
                buf[v*PAD + i] = acc;
            }
        }
        __syncthreads();
    }

    // ---------- pass 2: beta (bottom-up); store ratio = beta/prior in place ----------
    {   // leaves: ratio = emit / Z,  Z = sum_i prior_i * emit_i
        const int start = (1 << DEPTH) - 1, cnt = 1 << DEPTH;
        for (int v = start + tid; v < start + cnt; v += BLOCK) {
            const int xv = x[nodeBase + v];
            float e[C]; float Z = 0.f;
            #pragma unroll
            for (int i = 0; i < C; ++i) { e[i] = sB[i][xv]; Z += buf[v*PAD + i] * e[i]; }
            const float invZ = 1.f / Z;
            #pragma unroll
            for (int i = 0; i < C; ++i) buf[v*PAD + i] = e[i] * invZ;
        }
        __syncthreads();
    }
    for (int d = DEPTH - 1; d >= 0; --d) {
        const int start = (1 << d) - 1, cnt = 1 << d;
        for (int u = start + tid; u < start + cnt; u += BLOCK) {
            const int c1 = 2*u + 1, c2 = 2*u + 2;
            float r1[C], r2[C];
            #pragma unroll
            for (int i = 0; i < C; ++i) { r1[i] = buf[c1*PAD + i]; r2[i] = buf[c2*PAD + i]; }
            float prod[C];
            #pragma unroll
            for (int j = 0; j < C; ++j) {
                float a1 = 0.f, a2 = 0.f;
                #pragma unroll
                for (int i = 0; i < C; ++i) { a1 += sA[i][j]*r1[i]; a2 += sA[i][j]*r2[i]; }
                prod[j] = a1 * a2;   // product over the 2 children of beta_uv
            }
            const int xu = x[nodeBase + u];
            float pr[C], ep[C]; float Z = 0.f;
            #pragma unroll
            for (int j = 0; j < C; ++j) {
                ep[j] = sB[j][xu] * prod[j];
                pr[j] = buf[u*PAD + j];
                Z += pr[j] * ep[j];
            }
            const float invZ = 1.f / Z;
            if (u == 0) {   // root: store beta (= eps at root)
                #pragma unroll
                for (int j = 0; j < C; ++j) buf[j] = pr[j] * ep[j] * invZ;
            } else {        // ratio = beta/prior = emit*prod/Z
                #pragma unroll
                for (int j = 0; j < C; ++j) buf[u*PAD + j] = ep[j] * invZ;
            }
        }
        __syncthreads();
    }

    // ---------- pass 3: eps (top-down) + likelihood ----------
    float lik = 0.f;
    if (tid == 0) {     // root: (eps*logPi).sum + emission term
        const int xr = x[nodeBase];
        #pragma unroll
        for (int c = 0; c < C; ++c) lik += buf[c] * (lgpi[c] + lgB[c][xr]);
    }
    for (int d = 1; d <= DEPTH; ++d) {
        const int start = (1 << d) - 1, cnt = 1 << d;
        for (int v = start + tid; v < start + cnt; v += BLOCK) {
            const int pa = (v - 1) >> 1;
            float epa[C], r[C];
            #pragma unroll
            for (int j = 0; j < C; ++j) epa[j] = buf[pa*PAD + j];   // eps[parent]
            #pragma unroll
            for (int i = 0; i < C; ++i) r[i] = buf[v*PAD + i];      // ratio
            float f[C];
            #pragma unroll
            for (int j = 0; j < C; ++j) {                           // t_beta recomputed
                float tb = 0.f;
                #pragma unroll
                for (int i = 0; i < C; ++i) tb += sA[i][j] * r[i];
                f[j] = epa[j] / tb;
            }
            float num[C], S = 0.f, likA = 0.f;
            #pragma unroll
            for (int i = 0; i < C; ++i) {
                float a = 0.f, la = 0.f;
                #pragma unroll
                for (int j = 0; j < C; ++j) {
                    const float te = sA[i][j] * f[j];               // te/r[i]
                    a  += te;
                    la += te * lgA[i][j];
                }
                num[i] = r[i] * a;
                S     += num[i];
                likA  += r[i] * la;                                  // sum_ij t_eps*logA
            }
            const int xv = x[nodeBase + v];
            const float invS = 1.f / S;
            float likE = 0.f;
            #pragma unroll
            for (int i = 0; i < C; ++i) {
                const float e2 = num[i] * invS;                      // eps[v]
                buf[v*PAD + i] = e2;
                likE += e2 * lgB[i][xv];
            }
            lik += likA + likE;
        }
        __syncthreads();
    }

    // ---------- block reduction of lik ----------
    red[tid] = lik;
    __syncthreads();
    for (int off = BLOCK >> 1; off > 0; off >>= 1) {
        if (tid < off) red[tid] += red[tid + off];
        __syncthreads();
    }
    if (tid == 0) out[t*G + g] = -red[0];
}

extern "C" void kernel_launch(void* const* d_in, const int* in_sizes, int n_in,
                              void* d_out, int out_size, void* d_ws, size_t ws_size,
                              hipStream_t stream) {
    const float* A  = (const float*)d_in[0];
    const float* B  = (const float*)d_in[1];
    const float* Pi = (const float*)d_in[2];
    const int*   x  = (const int*)d_in[3];
    float* out = (float*)d_out;
    htmm_kernel<<<NTREES * G, BLOCK, 0, stream>>>(A, B, Pi, x, out);
}